// Round 9
// baseline (507.179 us; speedup 1.0000x reference)
//
#include <hip/hip_runtime.h>
#include <cmath>

typedef __attribute__((ext_vector_type(8))) short short8;
typedef __attribute__((ext_vector_type(8))) unsigned short ushort8_t;
typedef __attribute__((ext_vector_type(8))) _Float16 half8;
typedef __attribute__((ext_vector_type(4))) float f32x4;
typedef __attribute__((ext_vector_type(4))) unsigned int u32x4;
typedef unsigned short u16;

__device__ __forceinline__ u16 f2h(float f) {
    _Float16 h = (_Float16)f;
    return __builtin_bit_cast(u16, h);
}
__device__ __forceinline__ float h2f(u16 b) {
    return (float)__builtin_bit_cast(_Float16, b);
}
__device__ __forceinline__ short8 neg16(short8 v) {
    u32x4 u = __builtin_bit_cast(u32x4, v);
    u ^= 0x80008000u;
    return __builtin_bit_cast(short8, u);
}

#define GLD16(g, l)                                                              \
    __builtin_amdgcn_global_load_lds(                                            \
        (const __attribute__((address_space(1))) unsigned int*)(g),              \
        (__attribute__((address_space(3))) unsigned int*)(l), 16, 0, 0)

#define MFMA_F16(a, b, c)                                                        \
    __builtin_amdgcn_mfma_f32_16x16x32_f16(                                      \
        __builtin_bit_cast(half8, (a)), __builtin_bit_cast(half8, (b)), (c), 0, 0, 0)
#define SBAR() asm volatile("s_barrier" ::: "memory")

// all four f32 -> fp16 casts in one launch; grid 7168 (4096 x-blocks + 3072 W)
__global__ __launch_bounds__(256) void to_h_all(
    const float* __restrict__ x, const float* __restrict__ WQ,
    const float* __restrict__ WK, const float* __restrict__ WV,
    u16* __restrict__ xh, u16* __restrict__ Wh)
{
    int bid = blockIdx.x;
    const float* src;
    u16* dst;
    int off;
    if (bid < 4096) { src = x; dst = xh; off = bid; }
    else {
        int j = bid - 4096;
        int wsel = j >> 10;
        off = j & 1023;
        src = wsel == 0 ? WQ : (wsel == 1 ? WK : WV);
        dst = Wh + (size_t)wsel * 1024 * 1024;
    }
    int idx = off * 256 + threadIdx.x;
    float4 v = reinterpret_cast<const float4*>(src)[idx];
    ushort4 h;
    h.x = f2h(v.x); h.y = f2h(v.y); h.z = f2h(v.z); h.w = f2h(v.w);
    reinterpret_cast<ushort4*>(dst)[idx] = h;
}

// ============ 256x256 8-phase logits kernel, fp16, K=1024 ============
// S = Qh x Kh'^T: Hamilton perm on Kh's 256-col chunks; SIGN applied by
// negating the A-fragments in-register (wave-uniform per K-tile).
// Epilogue (barrier-free): per-wave 64-col stats pm/ps[row*64+tcol] and
// stores p = exp(S - rowmax_tile) as fp16 into P.
__global__ __launch_bounds__(512, 2) void logits8(
    const u16* __restrict__ A, const u16* __restrict__ B,
    u16* __restrict__ P, float* __restrict__ pm, float* __restrict__ ps,
    int perm_packed, int sign_packed)
{
    constexpr int NT = 16;
    __shared__ u16 L[2][2][256 * 64];
    const int tid = threadIdx.x;
    const int l = tid & 63, w = tid >> 6;
    const int wr = w >> 2, wc = w & 3;
    const int lr = l & 15, lh = l >> 4;
    const int bid = (int)blockIdx.x;
    const int swz = (bid & 7) * 32 + (bid >> 3);
    const int row0 = (swz >> 4) * 256, col0 = (swz & 15) * 256;
    const int srow = l >> 3;
    const int scol = ((l & 7) ^ (l >> 3)) * 8;

    f32x4 acc[8][4] = {};

    auto stage = [&](int t) {
        int kA = t * 64;
        int ch = kA >> 8;
        int p = (perm_packed >> (2 * ch)) & 3;
        int kB = (p << 8) + (kA & 255);
        int bf = t & 1;
        #pragma unroll
        for (int i = 0; i < 4; ++i) {
            int r0 = w * 32 + i * 8;
            GLD16(&A[(size_t)(row0 + r0 + srow) * 1024 + kA + scol], &L[bf][0][r0 * 64]);
        }
        #pragma unroll
        for (int i = 0; i < 4; ++i) {
            int r0 = w * 32 + i * 8;
            GLD16(&B[(size_t)(col0 + r0 + srow) * 1024 + kB + scol], &L[bf][1][r0 * 64]);
        }
    };
    auto readA = [&](int bf, int m, int kh) -> short8 {
        int row = wr * 128 + m * 16 + lr;
        int c = ((kh * 4 + lh) ^ (lr & 7)) * 8;
        return *reinterpret_cast<const short8*>(&L[bf][0][row * 64 + c]);
    };
    auto readB = [&](int bf, int n, int kh) -> short8 {
        int row = wc * 64 + n * 16 + lr;
        int c = ((kh * 4 + lh) ^ (lr & 7)) * 8;
        return *reinterpret_cast<const short8*>(&L[bf][1][row * 64 + c]);
    };

    stage(0);
    stage(1);
    asm volatile("s_waitcnt vmcnt(8)" ::: "memory");
    SBAR();

    #pragma unroll 2
    for (int t = 0; t < NT; ++t) {
        const int bf = t & 1;
        const bool sgn = (sign_packed >> (t >> 2)) & 1;
        short8 am[4][2], bn[4][2];
        // phase 0: read A m0-3 (+sign) + B n0-1; MFMA m0-3 x n0-1
        #pragma unroll
        for (int m = 0; m < 4; ++m) { am[m][0] = readA(bf, m, 0); am[m][1] = readA(bf, m, 1); }
        if (sgn)
            #pragma unroll
            for (int m = 0; m < 4; ++m) { am[m][0] = neg16(am[m][0]); am[m][1] = neg16(am[m][1]); }
        #pragma unroll
        for (int n = 0; n < 2; ++n) { bn[n][0] = readB(bf, n, 0); bn[n][1] = readB(bf, n, 1); }
        SBAR();
        __builtin_amdgcn_s_setprio(1);
        #pragma unroll
        for (int m = 0; m < 4; ++m)
            #pragma unroll
            for (int n = 0; n < 2; ++n) {
                acc[m][n] = MFMA_F16(am[m][0], bn[n][0], acc[m][n]);
                acc[m][n] = MFMA_F16(am[m][1], bn[n][1], acc[m][n]);
            }
        __builtin_amdgcn_s_setprio(0);
        SBAR();
        // phase 1: read B n2-3; MFMA m0-3 x n2-3
        #pragma unroll
        for (int n = 2; n < 4; ++n) { bn[n][0] = readB(bf, n, 0); bn[n][1] = readB(bf, n, 1); }
        SBAR();
        __builtin_amdgcn_s_setprio(1);
        #pragma unroll
        for (int m = 0; m < 4; ++m)
            #pragma unroll
            for (int n = 2; n < 4; ++n) {
                acc[m][n] = MFMA_F16(am[m][0], bn[n][0], acc[m][n]);
                acc[m][n] = MFMA_F16(am[m][1], bn[n][1], acc[m][n]);
            }
        __builtin_amdgcn_s_setprio(0);
        SBAR();
        // phase 2: read A m4-7 (+sign); MFMA m4-7 x n2-3
        #pragma unroll
        for (int m = 0; m < 4; ++m) { am[m][0] = readA(bf, 4 + m, 0); am[m][1] = readA(bf, 4 + m, 1); }
        if (sgn)
            #pragma unroll
            for (int m = 0; m < 4; ++m) { am[m][0] = neg16(am[m][0]); am[m][1] = neg16(am[m][1]); }
        SBAR();
        __builtin_amdgcn_s_setprio(1);
        #pragma unroll
        for (int m = 0; m < 4; ++m)
            #pragma unroll
            for (int n = 2; n < 4; ++n) {
                acc[4 + m][n] = MFMA_F16(am[m][0], bn[n][0], acc[4 + m][n]);
                acc[4 + m][n] = MFMA_F16(am[m][1], bn[n][1], acc[4 + m][n]);
            }
        __builtin_amdgcn_s_setprio(0);
        SBAR();
        // phase 3: stage t+2, MFMA m4-7 x n0-1
        if (t + 2 < NT) stage(t + 2);
        SBAR();
        __builtin_amdgcn_s_setprio(1);
        #pragma unroll
        for (int m = 0; m < 4; ++m)
            #pragma unroll
            for (int n = 0; n < 2; ++n) {
                acc[4 + m][n] = MFMA_F16(am[m][0], bn[n][0], acc[4 + m][n]);
                acc[4 + m][n] = MFMA_F16(am[m][1], bn[n][1], acc[4 + m][n]);
            }
        __builtin_amdgcn_s_setprio(0);
        if (t + 2 < NT) { asm volatile("s_waitcnt vmcnt(8)" ::: "memory"); }
        else           { asm volatile("s_waitcnt vmcnt(0)" ::: "memory"); }
        SBAR();
    }

    // ---- barrier-free fused stats + fp16 p-store epilogue ----
    const int tcol = (col0 >> 6) + wc;
    #pragma unroll
    for (int m = 0; m < 8; ++m) {
        #pragma unroll
        for (int j = 0; j < 4; ++j) {
            int row = row0 + wr * 128 + m * 16 + lh * 4 + j;
            float v = fmaxf(fmaxf(acc[m][0][j], acc[m][1][j]),
                            fmaxf(acc[m][2][j], acc[m][3][j]));
            #pragma unroll
            for (int off = 1; off < 16; off <<= 1) v = fmaxf(v, __shfl_xor(v, off, 16));
            float e[4];
            #pragma unroll
            for (int n = 0; n < 4; ++n) e[n] = expf(acc[m][n][j] - v);
            float s = e[0] + e[1] + e[2] + e[3];
            #pragma unroll
            for (int off = 1; off < 16; off <<= 1) s += __shfl_xor(s, off, 16);
            if (lr == 0) {
                pm[(size_t)row * 64 + tcol] = v;
                ps[(size_t)row * 64 + tcol] = s;
            }
            #pragma unroll
            for (int n = 0; n < 4; ++n) {
                int gc = col0 + wc * 64 + n * 16 + lr;
                P[(size_t)row * 4096 + gc] = f2h(e[n]);
            }
        }
    }
}

// ============ fused QKV projection, 8-phase 256x256, fp16 K=1024 ============
__global__ __launch_bounds__(512, 2) void qkv8(
    const u16* __restrict__ A, const u16* __restrict__ B,
    u16* __restrict__ Qh, u16* __restrict__ Kh, u16* __restrict__ Vt)
{
    constexpr int NT = 16;
    __shared__ u16 L[2][2][256 * 64];
    const int tid = threadIdx.x;
    const int l = tid & 63, w = tid >> 6;
    const int wr = w >> 2, wc = w & 3;
    const int lr = l & 15, lh = l >> 4;
    const int bid = (int)blockIdx.x;
    const int wgid = (bid & 7) * 24 + (bid >> 3);
    const int row0 = (wgid / 12) * 256, col0 = (wgid % 12) * 256;
    const int srow = l >> 3;
    const int scol = ((l & 7) ^ (l >> 3)) * 8;

    f32x4 acc[8][4] = {};

    auto stage = [&](int t) {
        int k0 = t * 64;
        int bf = t & 1;
        #pragma unroll
        for (int i = 0; i < 4; ++i) {
            int r0 = w * 32 + i * 8;
            GLD16(&A[(size_t)(row0 + r0 + srow) * 1024 + k0 + scol], &L[bf][0][r0 * 64]);
        }
        #pragma unroll
        for (int i = 0; i < 4; ++i) {
            int r0 = w * 32 + i * 8;
            GLD16(&B[(size_t)(col0 + r0 + srow) * 1024 + k0 + scol], &L[bf][1][r0 * 64]);
        }
    };
    auto readA = [&](int bf, int m, int kh) -> short8 {
        int row = wr * 128 + m * 16 + lr;
        int c = ((kh * 4 + lh) ^ (lr & 7)) * 8;
        return *reinterpret_cast<const short8*>(&L[bf][0][row * 64 + c]);
    };
    auto readB = [&](int bf, int n, int kh) -> short8 {
        int row = wc * 64 + n * 16 + lr;
        int c = ((kh * 4 + lh) ^ (lr & 7)) * 8;
        return *reinterpret_cast<const short8*>(&L[bf][1][row * 64 + c]);
    };

    stage(0);
    stage(1);
    asm volatile("s_waitcnt vmcnt(8)" ::: "memory");
    SBAR();

    #pragma unroll 2
    for (int t = 0; t < NT; ++t) {
        const int bf = t & 1;
        short8 am[4][2], bn[4][2];
        #pragma unroll
        for (int m = 0; m < 4; ++m) { am[m][0] = readA(bf, m, 0); am[m][1] = readA(bf, m, 1); }
        #pragma unroll
        for (int n = 0; n < 2; ++n) { bn[n][0] = readB(bf, n, 0); bn[n][1] = readB(bf, n, 1); }
        SBAR();
        __builtin_amdgcn_s_setprio(1);
        #pragma unroll
        for (int m = 0; m < 4; ++m)
            #pragma unroll
            for (int n = 0; n < 2; ++n) {
                acc[m][n] = MFMA_F16(am[m][0], bn[n][0], acc[m][n]);
                acc[m][n] = MFMA_F16(am[m][1], bn[n][1], acc[m][n]);
            }
        __builtin_amdgcn_s_setprio(0);
        SBAR();
        #pragma unroll
        for (int n = 2; n < 4; ++n) { bn[n][0] = readB(bf, n, 0); bn[n][1] = readB(bf, n, 1); }
        SBAR();
        __builtin_amdgcn_s_setprio(1);
        #pragma unroll
        for (int m = 0; m < 4; ++m)
            #pragma unroll
            for (int n = 2; n < 4; ++n) {
                acc[m][n] = MFMA_F16(am[m][0], bn[n][0], acc[m][n]);
                acc[m][n] = MFMA_F16(am[m][1], bn[n][1], acc[m][n]);
            }
        __builtin_amdgcn_s_setprio(0);
        SBAR();
        #pragma unroll
        for (int m = 0; m < 4; ++m) { am[m][0] = readA(bf, 4 + m, 0); am[m][1] = readA(bf, 4 + m, 1); }
        SBAR();
        __builtin_amdgcn_s_setprio(1);
        #pragma unroll
        for (int m = 0; m < 4; ++m)
            #pragma unroll
            for (int n = 2; n < 4; ++n) {
                acc[4 + m][n] = MFMA_F16(am[m][0], bn[n][0], acc[4 + m][n]);
                acc[4 + m][n] = MFMA_F16(am[m][1], bn[n][1], acc[4 + m][n]);
            }
        __builtin_amdgcn_s_setprio(0);
        SBAR();
        if (t + 2 < NT) stage(t + 2);
        SBAR();
        __builtin_amdgcn_s_setprio(1);
        #pragma unroll
        for (int m = 0; m < 4; ++m)
            #pragma unroll
            for (int n = 0; n < 2; ++n) {
                acc[4 + m][n] = MFMA_F16(am[m][0], bn[n][0], acc[4 + m][n]);
                acc[4 + m][n] = MFMA_F16(am[m][1], bn[n][1], acc[4 + m][n]);
            }
        __builtin_amdgcn_s_setprio(0);
        if (t + 2 < NT) { asm volatile("s_waitcnt vmcnt(8)" ::: "memory"); }
        else           { asm volatile("s_waitcnt vmcnt(0)" ::: "memory"); }
        SBAR();
    }

    const int mode = col0 >> 10;   // 0=Q, 1=K, 2=V (uniform per block)
    #pragma unroll
    for (int m = 0; m < 8; ++m)
        #pragma unroll
        for (int n = 0; n < 4; ++n) {
            int gr = row0 + wr * 128 + m * 16 + lh * 4;
            int gc = col0 + wc * 64 + n * 16 + lr;
            int gcl = gc & 1023;
            f32x4 v = acc[m][n];
            if (mode == 0) {
                #pragma unroll
                for (int j = 0; j < 4; ++j)
                    Qh[(size_t)(gr + j) * 1024 + gcl] = f2h(v[j]);
            } else if (mode == 1) {
                #pragma unroll
                for (int j = 0; j < 4; ++j)
                    Kh[(size_t)(gr + j) * 1024 + gcl] = f2h(v[j]);
            } else {
                ushort4 o;
                o.x = f2h(v[0]); o.y = f2h(v[1]); o.z = f2h(v[2]); o.w = f2h(v[3]);
                *reinterpret_cast<ushort4*>(&Vt[(size_t)gcl * 4096 + gr]) = o;
            }
        }
}

// ============ fused softmax + PV, split-K 8, p-fp16 input, atomic-y ============
// Reads p = fp16 exp(l - m_tile); w = p * alpha, alpha = exp(m_t - M)/S.
// fp16 MFMA vs Vt; f32 atomicAdd partials into y (y pre-zeroed).
template<bool WRITE_W>
__global__ __launch_bounds__(256) void pv_fused(
    const u16* __restrict__ P, float* __restrict__ Wout,
    const u16* __restrict__ Vt, const float* __restrict__ pm,
    const float* __restrict__ ps, float* __restrict__ Y, int c256)
{
    __shared__ u16 As[64 * 64];
    __shared__ u16 Bs[256 * 64];
    __shared__ float Red[64][4];
    __shared__ float Ms[64], Is[64];
    const int tid = threadIdx.x;
    const int l = tid & 63, w = tid >> 6;
    const int lr = l & 15, lh = l >> 4;
    const int kc = blockIdx.x;
    const int row0 = blockIdx.y * 64;
    const int kbase = kc * 512;
    const int srow = l >> 3, scol = ((l & 7) ^ (l >> 3)) * 8;

    // ---- global row stats from 64 per-tile partials ----
    {
        int row = tid & 63, part = tid >> 6;
        const float* pmr = &pm[(size_t)(row0 + row) * 64 + part * 16];
        const float* psr = &ps[(size_t)(row0 + row) * 64 + part * 16];
        float M = -INFINITY;
        #pragma unroll
        for (int i = 0; i < 16; ++i) M = fmaxf(M, pmr[i]);
        Red[row][part] = M;
        __syncthreads();
        float Mg = fmaxf(fmaxf(Red[row][0], Red[row][1]),
                         fmaxf(Red[row][2], Red[row][3]));
        float S = 0.f;
        #pragma unroll
        for (int i = 0; i < 16; ++i) S += psr[i] * expf(pmr[i] - Mg);
        __syncthreads();
        Red[row][part] = S;
        __syncthreads();
        if (tid < 64) {
            float Sg = Red[tid][0] + Red[tid][1] + Red[tid][2] + Red[tid][3];
            Ms[tid] = Mg;
            Is[tid] = 1.0f / Sg;
        }
        __syncthreads();
    }

    const int r0 = tid >> 3;            // rows handled: r0, r0+32
    const float M0 = Ms[r0], I0 = Is[r0];
    const float M1 = Ms[r0 + 32], I1 = Is[r0 + 32];

    f32x4 acc[4][4] = {};

    for (int kt = 0; kt < 8; ++kt) {
        const int tcol = kc * 8 + kt;
        __syncthreads();
        // stage A: w = p * alpha -> fp16, XOR-swizzled LDS write (2 rows/thread)
        #pragma unroll
        for (int i = 0; i < 2; ++i) {
            int r = r0 + i * 32;
            int s8 = tid & 7;
            float Mv = i ? M1 : M0, Iv = i ? I1 : I0;
            float alpha = expf(pm[(size_t)(row0 + r) * 64 + tcol] - Mv) * Iv;
            size_t ga = (size_t)(row0 + r) * 4096 + kbase + kt * 64 + s8 * 8;
            ushort8_t p8 = *reinterpret_cast<const ushort8_t*>(&P[ga]);
            ushort8_t w8;
            float wf[8];
            #pragma unroll
            for (int e = 0; e < 8; ++e) {
                wf[e] = h2f(p8[e]) * alpha;
                w8[e] = f2h(wf[e]);
            }
            if (WRITE_W) {
                *reinterpret_cast<float4*>(&Wout[ga]) =
                    make_float4(wf[0], wf[1], wf[2], wf[3]);
                *reinterpret_cast<float4*>(&Wout[ga + 4]) =
                    make_float4(wf[4], wf[5], wf[6], wf[7]);
            }
            *reinterpret_cast<ushort8_t*>(&As[r * 64 + (s8 ^ (r & 7)) * 8]) = w8;
        }
        // stage B: Vt rows c256..+256 x 64 k-cols (pre-swizzled source)
        #pragma unroll
        for (int i = 0; i < 8; ++i) {
            int rb = w * 64 + i * 8;
            GLD16(&Vt[(size_t)(c256 + rb + srow) * 4096 + kbase + kt * 64 + scol],
                  &Bs[rb * 64]);
        }
        __syncthreads();
        #pragma unroll
        for (int kh = 0; kh < 2; ++kh) {
            short8 af[4], bfv[4];
            #pragma unroll
            for (int m = 0; m < 4; ++m)
                af[m] = *reinterpret_cast<const short8*>(
                    &As[(m * 16 + lr) * 64 + ((kh * 4 + lh) ^ (lr & 7)) * 8]);
            #pragma unroll
            for (int n = 0; n < 4; ++n)
                bfv[n] = *reinterpret_cast<const short8*>(
                    &Bs[(w * 64 + n * 16 + lr) * 64 + ((kh * 4 + lh) ^ (lr & 7)) * 8]);
            #pragma unroll
            for (int m = 0; m < 4; ++m)
                #pragma unroll
                for (int n = 0; n < 4; ++n)
                    acc[m][n] = MFMA_F16(af[m], bfv[n], acc[m][n]);
        }
    }

    #pragma unroll
    for (int m = 0; m < 4; ++m)
        #pragma unroll
        for (int n = 0; n < 4; ++n) {
            int rr = m * 16 + lh * 4;
            int col = c256 + w * 64 + n * 16 + lr;
            #pragma unroll
            for (int j = 0; j < 4; ++j)
                atomicAdd(&Y[(size_t)(row0 + rr + j) * 1024 + col], acc[m][n][j]);
        }
}

extern "C" void kernel_launch(void* const* d_in, const int* in_sizes, int n_in,
                              void* d_out, int out_size, void* d_ws, size_t ws_size,
                              hipStream_t stream)
{
    const int n = 4096, d = 1024;
    const float* x  = (const float*)d_in[0];
    const float* WQ = (const float*)d_in[1];
    const float* WK = (const float*)d_in[2];
    const float* WV = (const float*)d_in[3];

    float* y = (float*)d_out;                  // [4096,1024]
    float* wout = y + (size_t)n * d;           // [4096,4096] final w (c=3 only)

    // ws layout. xh/Wh alias the P region (consumed by qkv8 before logits8
    // first writes P — stream-ordered).
    u16* P    = (u16*)d_ws;                    // [4096][4096] fp16 p (33.5 MB)
    u16* xh   = P;                             // [4096,1024] fp16 (alias)
    u16* Wh   = P + (size_t)n * 1024;          // [3072,1024] fp16 (alias)
    u16* Qh   = P + (size_t)n * 4096;          // [4096,1024] fp16
    u16* Kh   = Qh + (size_t)n * 1024;
    u16* Vt   = Kh + (size_t)n * 1024;         // [1024,4096] fp16 V^T
    float* pm = (float*)(Vt + (size_t)d * 4096);  // [4096][64]
    float* ps = pm + (size_t)n * 64;           // [4096][64]
    // total ws ~60.8 MB

    hipMemsetAsync(y, 0, (size_t)n * d * sizeof(float), stream);

    to_h_all<<<7168, 256, 0, stream>>>(x, WQ, WK, WV, xh, Wh);

    qkv8<<<192, 512, 0, stream>>>(xh, Wh, Qh, Kh, Vt);

    const int permv[4] = {0xE4, 0xB1, 0x4E, 0x1B};
    const int signv[4] = {0x0E, 0x08, 0x02, 0x04};

    for (int c = 0; c < 4; ++c) {
        logits8<<<256, 512, 0, stream>>>(Qh, Kh, P, pm, ps, permv[c], signv[c]);
        if (c == 3)
            pv_fused<true><<<dim3(8, 64), 256, 0, stream>>>(P, wout, Vt, pm, ps, y, c * 256);
        else
            pv_fused<false><<<dim3(8, 64), 256, 0, stream>>>(P, wout, Vt, pm, ps, y, c * 256);
    }
}

// Round 10
// 350.415 us; speedup vs baseline: 1.4474x; 1.4474x over previous
//
#include <hip/hip_runtime.h>
#include <cmath>

typedef __attribute__((ext_vector_type(8))) short short8;
typedef __attribute__((ext_vector_type(8))) unsigned short ushort8_t;
typedef __attribute__((ext_vector_type(8))) _Float16 half8;
typedef __attribute__((ext_vector_type(4))) float f32x4;
typedef unsigned short u16;

__device__ __forceinline__ u16 f2h(float f) {
    _Float16 h = (_Float16)f;
    return __builtin_bit_cast(u16, h);
}
__device__ __forceinline__ float h2f(u16 b) {
    return (float)__builtin_bit_cast(_Float16, b);
}

#define GLD16(g, l)                                                              \
    __builtin_amdgcn_global_load_lds(                                            \
        (const __attribute__((address_space(1))) unsigned int*)(g),              \
        (__attribute__((address_space(3))) unsigned int*)(l), 16, 0, 0)

#define MFMA_F16(a, b, c)                                                        \
    __builtin_amdgcn_mfma_f32_16x16x32_f16(                                      \
        __builtin_bit_cast(half8, (a)), __builtin_bit_cast(half8, (b)), (c), 0, 0, 0)
#define SBAR() asm volatile("s_barrier" ::: "memory")

// all four f32 -> fp16 casts in one launch; grid 7168 (4096 x-blocks + 3072 W)
__global__ __launch_bounds__(256) void to_h_all(
    const float* __restrict__ x, const float* __restrict__ WQ,
    const float* __restrict__ WK, const float* __restrict__ WV,
    u16* __restrict__ xh, u16* __restrict__ Wh)
{
    int bid = blockIdx.x;
    const float* src;
    u16* dst;
    int off;
    if (bid < 4096) { src = x; dst = xh; off = bid; }
    else {
        int j = bid - 4096;
        int wsel = j >> 10;
        off = j & 1023;
        src = wsel == 0 ? WQ : (wsel == 1 ? WK : WV);
        dst = Wh + (size_t)wsel * 1024 * 1024;
    }
    int idx = off * 256 + threadIdx.x;
    float4 v = reinterpret_cast<const float4*>(src)[idx];
    ushort4 h;
    h.x = f2h(v.x); h.y = f2h(v.y); h.z = f2h(v.z); h.w = f2h(v.w);
    reinterpret_cast<ushort4*>(dst)[idx] = h;
}

// ============ 256x256 8-phase logits kernel, fp16, K=1024 ============
// S = Qh x Kh'^T (Hamilton perm on Kh cols; sign via pre-negated Khn).
// Epilogue: wave-local LDS transpose (no barriers), per-64-col stats
// pm/ps[row*64+tcol], coalesced fp16 store of D = S - rowmax_tile.
__global__ __launch_bounds__(512, 2) void logits8(
    const u16* __restrict__ A, const u16* __restrict__ B, const u16* __restrict__ Bneg,
    u16* __restrict__ Ch, float* __restrict__ pm, float* __restrict__ ps,
    int perm_packed, int sign_packed)
{
    constexpr int NT = 16;
    __shared__ u16 L[2][2][256 * 64];
    const int tid = threadIdx.x;
    const int l = tid & 63, w = tid >> 6;
    const int wr = w >> 2, wc = w & 3;
    const int lr = l & 15, lh = l >> 4;
    const int bid = (int)blockIdx.x;
    const int swz = (bid & 7) * 32 + (bid >> 3);
    const int row0 = (swz >> 4) * 256, col0 = (swz & 15) * 256;
    const int srow = l >> 3;
    const int scol = ((l & 7) ^ (l >> 3)) * 8;

    f32x4 acc[8][4] = {};

    auto stage = [&](int t) {
        int kA = t * 64;
        int ch = kA >> 8;
        int p = (perm_packed >> (2 * ch)) & 3;
        const u16* Bsrc = ((sign_packed >> ch) & 1) ? Bneg : B;
        int kB = (p << 8) + (kA & 255);
        int bf = t & 1;
        #pragma unroll
        for (int i = 0; i < 4; ++i) {
            int r0 = w * 32 + i * 8;
            GLD16(&A[(size_t)(row0 + r0 + srow) * 1024 + kA + scol], &L[bf][0][r0 * 64]);
        }
        #pragma unroll
        for (int i = 0; i < 4; ++i) {
            int r0 = w * 32 + i * 8;
            GLD16(&Bsrc[(size_t)(col0 + r0 + srow) * 1024 + kB + scol], &L[bf][1][r0 * 64]);
        }
    };
    auto readA = [&](int bf, int m, int kh) -> short8 {
        int row = wr * 128 + m * 16 + lr;
        int c = ((kh * 4 + lh) ^ (lr & 7)) * 8;
        return *reinterpret_cast<const short8*>(&L[bf][0][row * 64 + c]);
    };
    auto readB = [&](int bf, int n, int kh) -> short8 {
        int row = wc * 64 + n * 16 + lr;
        int c = ((kh * 4 + lh) ^ (lr & 7)) * 8;
        return *reinterpret_cast<const short8*>(&L[bf][1][row * 64 + c]);
    };

    stage(0);
    stage(1);
    asm volatile("s_waitcnt vmcnt(8)" ::: "memory");
    SBAR();

    #pragma unroll 2
    for (int t = 0; t < NT; ++t) {
        const int bf = t & 1;
        short8 am[4][2], bn[4][2];
        #pragma unroll
        for (int m = 0; m < 4; ++m) { am[m][0] = readA(bf, m, 0); am[m][1] = readA(bf, m, 1); }
        #pragma unroll
        for (int n = 0; n < 2; ++n) { bn[n][0] = readB(bf, n, 0); bn[n][1] = readB(bf, n, 1); }
        SBAR();
        __builtin_amdgcn_s_setprio(1);
        #pragma unroll
        for (int m = 0; m < 4; ++m)
            #pragma unroll
            for (int n = 0; n < 2; ++n) {
                acc[m][n] = MFMA_F16(am[m][0], bn[n][0], acc[m][n]);
                acc[m][n] = MFMA_F16(am[m][1], bn[n][1], acc[m][n]);
            }
        __builtin_amdgcn_s_setprio(0);
        SBAR();
        #pragma unroll
        for (int n = 2; n < 4; ++n) { bn[n][0] = readB(bf, n, 0); bn[n][1] = readB(bf, n, 1); }
        SBAR();
        __builtin_amdgcn_s_setprio(1);
        #pragma unroll
        for (int m = 0; m < 4; ++m)
            #pragma unroll
            for (int n = 2; n < 4; ++n) {
                acc[m][n] = MFMA_F16(am[m][0], bn[n][0], acc[m][n]);
                acc[m][n] = MFMA_F16(am[m][1], bn[n][1], acc[m][n]);
            }
        __builtin_amdgcn_s_setprio(0);
        SBAR();
        #pragma unroll
        for (int m = 0; m < 4; ++m) { am[m][0] = readA(bf, 4 + m, 0); am[m][1] = readA(bf, 4 + m, 1); }
        SBAR();
        __builtin_amdgcn_s_setprio(1);
        #pragma unroll
        for (int m = 0; m < 4; ++m)
            #pragma unroll
            for (int n = 2; n < 4; ++n) {
                acc[4 + m][n] = MFMA_F16(am[m][0], bn[n][0], acc[4 + m][n]);
                acc[4 + m][n] = MFMA_F16(am[m][1], bn[n][1], acc[4 + m][n]);
            }
        __builtin_amdgcn_s_setprio(0);
        SBAR();
        if (t + 2 < NT) stage(t + 2);
        SBAR();
        __builtin_amdgcn_s_setprio(1);
        #pragma unroll
        for (int m = 0; m < 4; ++m)
            #pragma unroll
            for (int n = 0; n < 2; ++n) {
                acc[4 + m][n] = MFMA_F16(am[m][0], bn[n][0], acc[4 + m][n]);
                acc[4 + m][n] = MFMA_F16(am[m][1], bn[n][1], acc[4 + m][n]);
            }
        __builtin_amdgcn_s_setprio(0);
        if (t + 2 < NT) { asm volatile("s_waitcnt vmcnt(8)" ::: "memory"); }
        else           { asm volatile("s_waitcnt vmcnt(0)" ::: "memory"); }
        SBAR();
    }

    // ---- wave-local LDS-transpose epilogue (no cross-wave sync needed:
    // all waves passed the loop's final SBAR; each wave uses a private
    // 16x68 f32 region; pitch 68 keeps LDS aliasing at free 2-way). ----
    const int tcol = (col0 >> 6) + wc;
    float* T = reinterpret_cast<float*>(&L[0][0][0]) + w * 1088;   // 16*68 f32
    const int rq = l >> 2;          // row within 16-row m-group
    const int cq = l & 3;           // 16-col quarter
    #pragma unroll
    for (int m = 0; m < 8; ++m) {
        #pragma unroll
        for (int n = 0; n < 4; ++n)
            #pragma unroll
            for (int j = 0; j < 4; ++j)
                T[(lh * 4 + j) * 68 + n * 16 + lr] = acc[m][n][j];
        float vals[16];
        #pragma unroll
        for (int q = 0; q < 4; ++q) {
            f32x4 v4 = *reinterpret_cast<const f32x4*>(&T[rq * 68 + cq * 16 + q * 4]);
            vals[q * 4 + 0] = v4[0]; vals[q * 4 + 1] = v4[1];
            vals[q * 4 + 2] = v4[2]; vals[q * 4 + 3] = v4[3];
        }
        float mx = vals[0];
        #pragma unroll
        for (int c = 1; c < 16; ++c) mx = fmaxf(mx, vals[c]);
        mx = fmaxf(mx, __shfl_xor(mx, 1, 64));
        mx = fmaxf(mx, __shfl_xor(mx, 2, 64));
        float s = 0.f;
        #pragma unroll
        for (int c = 0; c < 16; ++c) s += expf(vals[c] - mx);
        s += __shfl_xor(s, 1, 64);
        s += __shfl_xor(s, 2, 64);
        int row = row0 + wr * 128 + m * 16 + rq;
        if (cq == 0) {
            pm[(size_t)row * 64 + tcol] = mx;
            ps[(size_t)row * 64 + tcol] = s;
        }
        ushort8_t d0, d1;
        #pragma unroll
        for (int c = 0; c < 8; ++c) d0[c] = f2h(vals[c] - mx);
        #pragma unroll
        for (int c = 0; c < 8; ++c) d1[c] = f2h(vals[c + 8] - mx);
        size_t go = (size_t)row * 4096 + col0 + wc * 64 + cq * 16;
        *reinterpret_cast<ushort8_t*>(&Ch[go]) = d0;
        *reinterpret_cast<ushort8_t*>(&Ch[go + 8]) = d1;
    }
}

// ============ fused QKV projection, 8-phase 256x256, fp16 K=1024 ============
__global__ __launch_bounds__(512, 2) void qkv8(
    const u16* __restrict__ A, const u16* __restrict__ B,
    u16* __restrict__ Qh, u16* __restrict__ Kh, u16* __restrict__ Khn,
    u16* __restrict__ Vt)
{
    constexpr int NT = 16;
    __shared__ u16 L[2][2][256 * 64];
    const int tid = threadIdx.x;
    const int l = tid & 63, w = tid >> 6;
    const int wr = w >> 2, wc = w & 3;
    const int lr = l & 15, lh = l >> 4;
    const int bid = (int)blockIdx.x;
    const int wgid = (bid & 7) * 24 + (bid >> 3);
    const int row0 = (wgid / 12) * 256, col0 = (wgid % 12) * 256;
    const int srow = l >> 3;
    const int scol = ((l & 7) ^ (l >> 3)) * 8;

    f32x4 acc[8][4] = {};

    auto stage = [&](int t) {
        int k0 = t * 64;
        int bf = t & 1;
        #pragma unroll
        for (int i = 0; i < 4; ++i) {
            int r0 = w * 32 + i * 8;
            GLD16(&A[(size_t)(row0 + r0 + srow) * 1024 + k0 + scol], &L[bf][0][r0 * 64]);
        }
        #pragma unroll
        for (int i = 0; i < 4; ++i) {
            int r0 = w * 32 + i * 8;
            GLD16(&B[(size_t)(col0 + r0 + srow) * 1024 + k0 + scol], &L[bf][1][r0 * 64]);
        }
    };
    auto readA = [&](int bf, int m, int kh) -> short8 {
        int row = wr * 128 + m * 16 + lr;
        int c = ((kh * 4 + lh) ^ (lr & 7)) * 8;
        return *reinterpret_cast<const short8*>(&L[bf][0][row * 64 + c]);
    };
    auto readB = [&](int bf, int n, int kh) -> short8 {
        int row = wc * 64 + n * 16 + lr;
        int c = ((kh * 4 + lh) ^ (lr & 7)) * 8;
        return *reinterpret_cast<const short8*>(&L[bf][1][row * 64 + c]);
    };

    stage(0);
    stage(1);
    asm volatile("s_waitcnt vmcnt(8)" ::: "memory");
    SBAR();

    #pragma unroll 2
    for (int t = 0; t < NT; ++t) {
        const int bf = t & 1;
        short8 am[4][2], bn[4][2];
        #pragma unroll
        for (int m = 0; m < 4; ++m) { am[m][0] = readA(bf, m, 0); am[m][1] = readA(bf, m, 1); }
        #pragma unroll
        for (int n = 0; n < 2; ++n) { bn[n][0] = readB(bf, n, 0); bn[n][1] = readB(bf, n, 1); }
        SBAR();
        __builtin_amdgcn_s_setprio(1);
        #pragma unroll
        for (int m = 0; m < 4; ++m)
            #pragma unroll
            for (int n = 0; n < 2; ++n) {
                acc[m][n] = MFMA_F16(am[m][0], bn[n][0], acc[m][n]);
                acc[m][n] = MFMA_F16(am[m][1], bn[n][1], acc[m][n]);
            }
        __builtin_amdgcn_s_setprio(0);
        SBAR();
        #pragma unroll
        for (int n = 2; n < 4; ++n) { bn[n][0] = readB(bf, n, 0); bn[n][1] = readB(bf, n, 1); }
        SBAR();
        __builtin_amdgcn_s_setprio(1);
        #pragma unroll
        for (int m = 0; m < 4; ++m)
            #pragma unroll
            for (int n = 2; n < 4; ++n) {
                acc[m][n] = MFMA_F16(am[m][0], bn[n][0], acc[m][n]);
                acc[m][n] = MFMA_F16(am[m][1], bn[n][1], acc[m][n]);
            }
        __builtin_amdgcn_s_setprio(0);
        SBAR();
        #pragma unroll
        for (int m = 0; m < 4; ++m) { am[m][0] = readA(bf, 4 + m, 0); am[m][1] = readA(bf, 4 + m, 1); }
        SBAR();
        __builtin_amdgcn_s_setprio(1);
        #pragma unroll
        for (int m = 0; m < 4; ++m)
            #pragma unroll
            for (int n = 2; n < 4; ++n) {
                acc[4 + m][n] = MFMA_F16(am[m][0], bn[n][0], acc[4 + m][n]);
                acc[4 + m][n] = MFMA_F16(am[m][1], bn[n][1], acc[4 + m][n]);
            }
        __builtin_amdgcn_s_setprio(0);
        SBAR();
        if (t + 2 < NT) stage(t + 2);
        SBAR();
        __builtin_amdgcn_s_setprio(1);
        #pragma unroll
        for (int m = 0; m < 4; ++m)
            #pragma unroll
            for (int n = 0; n < 2; ++n) {
                acc[4 + m][n] = MFMA_F16(am[m][0], bn[n][0], acc[4 + m][n]);
                acc[4 + m][n] = MFMA_F16(am[m][1], bn[n][1], acc[4 + m][n]);
            }
        __builtin_amdgcn_s_setprio(0);
        if (t + 2 < NT) { asm volatile("s_waitcnt vmcnt(8)" ::: "memory"); }
        else           { asm volatile("s_waitcnt vmcnt(0)" ::: "memory"); }
        SBAR();
    }

    const int mode = col0 >> 10;   // 0=Q, 1=K, 2=V (uniform per block)
    #pragma unroll
    for (int m = 0; m < 8; ++m)
        #pragma unroll
        for (int n = 0; n < 4; ++n) {
            int gr = row0 + wr * 128 + m * 16 + lh * 4;
            int gc = col0 + wc * 64 + n * 16 + lr;
            int gcl = gc & 1023;
            f32x4 v = acc[m][n];
            if (mode == 0) {
                #pragma unroll
                for (int j = 0; j < 4; ++j)
                    Qh[(size_t)(gr + j) * 1024 + gcl] = f2h(v[j]);
            } else if (mode == 1) {
                #pragma unroll
                for (int j = 0; j < 4; ++j) {
                    u16 h = f2h(v[j]);
                    size_t o = (size_t)(gr + j) * 1024 + gcl;
                    Kh[o] = h; Khn[o] = h ^ 0x8000;
                }
            } else {
                ushort4 o;
                o.x = f2h(v[0]); o.y = f2h(v[1]); o.z = f2h(v[2]); o.w = f2h(v[3]);
                *reinterpret_cast<ushort4*>(&Vt[(size_t)gcl * 4096 + gr]) = o;
            }
        }
}

// ============ fused softmax + PV, split-K 8, fp16 D-logits ============
template<bool WRITE_W>
__global__ __launch_bounds__(256) void pv_fused(
    const u16* __restrict__ Lh, float* __restrict__ Wout,
    const u16* __restrict__ Vt, const float* __restrict__ pm,
    const float* __restrict__ ps, u16* __restrict__ ypart, int c256)
{
    __shared__ u16 As[64 * 64];
    __shared__ u16 Bs[256 * 64];
    __shared__ float Red[64][4];
    __shared__ float Ms[64], Is[64];
    const int tid = threadIdx.x;
    const int l = tid & 63, w = tid >> 6;
    const int lr = l & 15, lh = l >> 4;
    const int kc = blockIdx.x;
    const int row0 = blockIdx.y * 64;
    const int kbase = kc * 512;
    const int srow = l >> 3, scol = ((l & 7) ^ (l >> 3)) * 8;

    {
        int row = tid & 63, part = tid >> 6;
        const float* pmr = &pm[(size_t)(row0 + row) * 64 + part * 16];
        const float* psr = &ps[(size_t)(row0 + row) * 64 + part * 16];
        float M = -INFINITY;
        #pragma unroll
        for (int i = 0; i < 16; ++i) M = fmaxf(M, pmr[i]);
        Red[row][part] = M;
        __syncthreads();
        float Mg = fmaxf(fmaxf(Red[row][0], Red[row][1]),
                         fmaxf(Red[row][2], Red[row][3]));
        float S = 0.f;
        #pragma unroll
        for (int i = 0; i < 16; ++i) S += psr[i] * expf(pmr[i] - Mg);
        __syncthreads();
        Red[row][part] = S;
        __syncthreads();
        if (tid < 64) {
            float Sg = Red[tid][0] + Red[tid][1] + Red[tid][2] + Red[tid][3];
            Ms[tid] = Mg;
            Is[tid] = 1.0f / Sg;
        }
        __syncthreads();
    }

    float Mr[4], Ir[4];
    #pragma unroll
    for (int i = 0; i < 4; ++i) { int r = (tid >> 4) + i * 16; Mr[i] = Ms[r]; Ir[i] = Is[r]; }

    f32x4 acc[4][4] = {};

    for (int kt = 0; kt < 8; ++kt) {
        const int tcol = kc * 8 + kt;
        __syncthreads();
        #pragma unroll
        for (int i = 0; i < 4; ++i) {
            int idx = tid + i * 256;
            int r = idx >> 4, s4 = idx & 15;
            float coff = pm[(size_t)(row0 + r) * 64 + tcol] - Mr[i];
            size_t ga = (size_t)(row0 + r) * 4096 + kbase + kt * 64 + s4 * 4;
            ushort4 dv = *reinterpret_cast<const ushort4*>(&Lh[ga]);
            float e0 = expf(h2f(dv.x) + coff) * Ir[i];
            float e1 = expf(h2f(dv.y) + coff) * Ir[i];
            float e2 = expf(h2f(dv.z) + coff) * Ir[i];
            float e3 = expf(h2f(dv.w) + coff) * Ir[i];
            if (WRITE_W)
                *reinterpret_cast<float4*>(&Wout[ga]) = make_float4(e0, e1, e2, e3);
            ushort4 h;
            h.x = f2h(e0); h.y = f2h(e1); h.z = f2h(e2); h.w = f2h(e3);
            int dst = ((s4 >> 1) ^ (r & 7)) * 8 + (s4 & 1) * 4;
            *reinterpret_cast<ushort4*>(&As[r * 64 + dst]) = h;
        }
        #pragma unroll
        for (int i = 0; i < 8; ++i) {
            int r0 = w * 64 + i * 8;
            GLD16(&Vt[(size_t)(c256 + r0 + srow) * 4096 + kbase + kt * 64 + scol],
                  &Bs[r0 * 64]);
        }
        __syncthreads();
        #pragma unroll
        for (int kh = 0; kh < 2; ++kh) {
            short8 af[4], bfv[4];
            #pragma unroll
            for (int m = 0; m < 4; ++m)
                af[m] = *reinterpret_cast<const short8*>(
                    &As[(m * 16 + lr) * 64 + ((kh * 4 + lh) ^ (lr & 7)) * 8]);
            #pragma unroll
            for (int n = 0; n < 4; ++n)
                bfv[n] = *reinterpret_cast<const short8*>(
                    &Bs[(w * 64 + n * 16 + lr) * 64 + ((kh * 4 + lh) ^ (lr & 7)) * 8]);
            #pragma unroll
            for (int m = 0; m < 4; ++m)
                #pragma unroll
                for (int n = 0; n < 4; ++n)
                    acc[m][n] = MFMA_F16(af[m], bfv[n], acc[m][n]);
        }
    }

    #pragma unroll
    for (int m = 0; m < 4; ++m)
        #pragma unroll
        for (int n = 0; n < 4; ++n) {
            int rr = m * 16 + lh * 4;
            int col = w * 64 + n * 16 + lr;
            #pragma unroll
            for (int j = 0; j < 4; ++j)
                ypart[((size_t)kc * 4096 + row0 + rr + j) * 256 + col] = f2h(acc[m][n][j]);
        }
}

// y[:, c256..c256+256] = sum over 8 k-chunk fp16 partials (f32 accumulate)
__global__ __launch_bounds__(256) void reduce_y(const u16* __restrict__ ypart,
                                                float* __restrict__ y, int c256)
{
    int idx = blockIdx.x * 256 + threadIdx.x;
    int r = idx >> 6, c4 = (idx & 63) * 4;
    float s0 = 0.f, s1 = 0.f, s2 = 0.f, s3 = 0.f;
    #pragma unroll
    for (int kc = 0; kc < 8; ++kc) {
        ushort4 p = *reinterpret_cast<const ushort4*>(
            &ypart[((size_t)kc * 4096 + r) * 256 + c4]);
        s0 += h2f(p.x); s1 += h2f(p.y); s2 += h2f(p.z); s3 += h2f(p.w);
    }
    *reinterpret_cast<float4*>(&y[(size_t)r * 1024 + c256 + c4]) =
        make_float4(s0, s1, s2, s3);
}

extern "C" void kernel_launch(void* const* d_in, const int* in_sizes, int n_in,
                              void* d_out, int out_size, void* d_ws, size_t ws_size,
                              hipStream_t stream)
{
    const int n = 4096, d = 1024;
    const float* x  = (const float*)d_in[0];
    const float* WQ = (const float*)d_in[1];
    const float* WK = (const float*)d_in[2];
    const float* WV = (const float*)d_in[3];

    float* y = (float*)d_out;                  // [4096,1024]
    float* wout = y + (size_t)n * d;           // [4096,4096] final w (c=3 only)

    // ws layout. xh/Wh alias the Lh region (consumed by qkv8 before logits8
    // first writes Lh — stream-ordered).
    u16* Lh   = (u16*)d_ws;                    // [4096][4096] fp16 D  (33.5 MB)
    u16* xh   = Lh;                            // [4096,1024] fp16 (alias)
    u16* Wh   = Lh + (size_t)n * 1024;         // [3072,1024] fp16 (alias)
    u16* Qh   = Lh + (size_t)n * 4096;         // [4096,1024] fp16
    u16* Kh   = Qh  + (size_t)n * 1024;
    u16* Khn  = Kh  + (size_t)n * 1024;
    u16* Vt   = Khn + (size_t)n * 1024;        // [1024,4096] fp16 V^T
    u16* ypart = Vt + (size_t)d * 4096;        // [8][4096][256] fp16 (16 MB)
    float* pm = (float*)(ypart + (size_t)8 * n * 256);   // [4096][64]
    float* ps = pm + (size_t)n * 64;           // [4096][64]
    // total ws ~83.5 MB

    to_h_all<<<7168, 256, 0, stream>>>(x, WQ, WK, WV, xh, Wh);

    qkv8<<<192, 512, 0, stream>>>(xh, Wh, Qh, Kh, Khn, Vt);

    const int permv[4] = {0xE4, 0xB1, 0x4E, 0x1B};
    const int signv[4] = {0x0E, 0x08, 0x02, 0x04};

    for (int c = 0; c < 4; ++c) {
        logits8<<<256, 512, 0, stream>>>(Qh, Kh, Khn, Lh, pm, ps, permv[c], signv[c]);
        if (c == 3)
            pv_fused<true><<<dim3(8, 64), 256, 0, stream>>>(Lh, wout, Vt, pm, ps, ypart, c * 256);
        else
            pv_fused<false><<<dim3(8, 64), 256, 0, stream>>>(Lh, wout, Vt, pm, ps, ypart, c * 256);
        reduce_y<<<1024, 256, 0, stream>>>(ypart, y, c * 256);
    }
}